// Round 15
// baseline (499.004 us; speedup 1.0000x reference)
//
#include <hip/hip_runtime.h>
#include <stdint.h>

namespace {

constexpr int   B_   = 64;
constexpr int   F0_  = 1876;
constexpr int   F1_  = 1024;
constexpr int   F2_  = 10;
constexpr int   NT_  = 151;
constexpr float DT_  = 0.02f;
constexpr float SCL_  = 1073741824.0f;      // 2^30 fixed-point scale
constexpr float ISCL_ = 1.0f / 1073741824.0f;

constexpr int NBLK_T = 480;                  // 30 i-tiles x 16 j-tiles
constexpr int NBLK_R = 469;                  // 64*1876/256 (exact)

// workspace layout (bytes)
constexpr size_t OFF_W1IT = 0;                     // 1876*1024*4 = 7,684,096
constexpr size_t OFF_REC  = 7684096;               // 64*1876*8   =   960,512
constexpr size_t OFF_IDX1 = OFF_REC + 960512;      // 64*1024 u8  =    65,536

// ---------------------------------------------------------------------------
// k_prep: (a) blocks < 480: W1[j][i] (f32) -> W1iT[i][j] = rn(w * 2^30) (int)
//         (b) blocks >= 480: rec[b*1876+i] = { k*2048, ti_bits },
//             k = min(ceil(ti*50), 50)  (2048 = bins row stride in bytes).
// ---------------------------------------------------------------------------
__global__ __launch_bounds__(256) void k_prep(const float* __restrict__ W1,
                                              const float* __restrict__ ti,
                                              int* __restrict__ W1iT,
                                              uint2* __restrict__ rec) {
  const int t = threadIdx.x;
  if (blockIdx.x < NBLK_T) {
    __shared__ float tile[64][65];
    const int bx = blockIdx.x;
    const int i0 = (bx % 30) * 64;     // 0..1919
    const int j0 = (bx / 30) * 64;
    const int c = t & 63, r4 = t >> 6;
    for (int jj = r4; jj < 64; jj += 4) {
      int i = i0 + c;
      tile[c][jj] = (i < F0_) ? W1[(size_t)(j0 + jj) * F0_ + i] : 0.0f;
    }
    __syncthreads();
    for (int ii = r4; ii < 64; ii += 4) {
      int i = i0 + ii;
      if (i < F0_)
        W1iT[(size_t)i * F1_ + j0 + c] = __float2int_rn(tile[ii][c] * SCL_);
    }
  } else {
    int n = (blockIdx.x - NBLK_T) * 256 + t;
    if (n < B_ * F0_) {
      float v = ti[n];
      int k = (int)fminf(ceilf(v * 50.0f), 50.0f);   // ti >= 0 -> k >= 0
      rec[n] = make_uint2((uint32_t)k << 11, __float_as_uint(v));
    }
  }
}

// ---------------------------------------------------------------------------
// Layer 1, lane = j (the r14 lesson: random-k scatter has an irreducible
// ~8-cyc/op bank cost; wave-uniform k is conflict-free BY CONSTRUCTION).
// 256 blocks = b*4 + jg; 256 threads; thread tid owns column j = jg*256+tid.
// Stream i = 0..1875: rec broadcast from LDS (staged once, 15 KB), W1iT row
// slice coalesced 1 KB/block-row — all induction-addressed vector loads,
// no gathers, no scalar-load chains.  Per element ONE ds_add_u64 at
// bins[k][tid]: k uniform across the wave -> stride-1, 4 lanes/bank-pair
// (u64 floor), zero conflicts, zero same-address contention (tid owns cell).
// Packed pk = (a<<32)|(c mod 2^32) int sums -> bit-deterministic (r13/r14).
// Phase 2: per-thread 51-bin unpack+prefix fused into 151-step crossing.
// LDS 119 KB -> 1 block/CU.
// ---------------------------------------------------------------------------
__global__ __launch_bounds__(256) void k_main1(const uint2* __restrict__ rec,
                                               const int* __restrict__ W1iT,
                                               uint8_t* __restrict__ idx1) {
  __shared__ unsigned long long bins[51][256];   // 104,448 B
  __shared__ uint2 recs[F0_];                    //  15,008 B
  const int blk = blockIdx.x;         // 256
  const int b   = blk >> 2;
  const int jg  = blk & 3;
  const int tid = threadIdx.x;

  {
    int4* p = (int4*)(&bins[0][0]);
    for (int s = tid; s < (int)(sizeof(bins) / 16); s += 256)
      p[s] = make_int4(0, 0, 0, 0);
    const uint4* src = (const uint4*)(rec + (size_t)b * F0_);
    uint4* dst = (uint4*)recs;
    for (int s = tid; s < F0_ / 2; s += 256) dst[s] = src[s];   // 938 uint4
  }
  __syncthreads();

  const int* __restrict__ wcol = W1iT + (jg << 8) + tid;  // row stride 1024
  char* const binbase = (char*)(&bins[0][0]) + (tid << 3);

#pragma unroll 4
  for (int i = 0; i < F0_; ++i) {
    int   a  = wcol[(size_t)i << 10];        // coalesced 1 KB, L2-resident
    uint2 r  = recs[i];                      // LDS broadcast (uniform addr)
    float tv = __uint_as_float(r.y);
    int   c  = __float2int_rn((float)a * tv);
    unsigned long long pk =
        ((unsigned long long)(unsigned)a << 32) | (unsigned)c;
    atomicAdd((unsigned long long*)(binbase + r.x), pk);   // ds_add_u64
  }
  __syncthreads();

  // phase 2: per-thread prefix over bins fused with crossing scan
  float sa = 0.f, sc = 0.f;
  int cnd = NT_;
#pragma unroll 1
  for (int tt = 0; tt < NT_; ++tt) {
    if (tt < 51) {
      unsigned long long s = bins[tt][tid];
      int cl = (int)(unsigned)(s & 0xFFFFFFFFull);
      int ah = (int)(unsigned)(s >> 32);
      if (cl < 0) ah += 1;                   // borrow correction (exact)
      sa += (float)ah * ISCL_;
      sc += (float)cl * ISCL_;
    }
    float mv = (float)tt * DT_ * sa - sc;
    if (cnd == NT_ && mv >= 1.0f) cnd = tt;
  }
  cnd = min(cnd, NT_ - 1);                   // forced spike at last timestep
  idx1[((size_t)b << 10) + (jg << 8) + tid] = (uint8_t)cnd;
}

// ---------------------------------------------------------------------------
// Layer-2: brute force. Block = (b,j), 4 waves split the i-range; lane = t.
// (unchanged, proven)
// ---------------------------------------------------------------------------
__global__ __launch_bounds__(256) void k_main2(const uint8_t* __restrict__ idx1,
                                               const float* __restrict__ W2,
                                               float* __restrict__ out) {
  __shared__ float wrow[F1_];
  __shared__ float tirow[F1_];
  __shared__ float part[4][3][64];
  const int blk = blockIdx.x;          // 640
  const int b   = blk / 10;
  const int j   = blk - b * 10;
  const int tid = threadIdx.x;
  const int lane = tid & 63, wvv = tid >> 6;

  const float*   w = W2  + (size_t)j * F1_;
  const uint8_t* h = idx1 + (size_t)b * F1_;
  for (int s = tid; s < F1_; s += 256) {
    wrow[s]  = w[s];
    tirow[s] = (float)h[s] * DT_;
  }
  __syncthreads();

  const float tl0 = (float)lane * DT_;
  const float tl1 = (float)(lane + 64) * DT_;
  const float tl2 = (float)(lane + 128) * DT_;
  float m0 = 0.f, m1 = 0.f, m2 = 0.f;
  const int i0 = wvv * 256;
#pragma unroll 4
  for (int i = i0; i < i0 + 256; ++i) {
    float tiv = tirow[i], ww = wrow[i];
    m0 = fmaf(ww, fmaxf(tl0 - tiv, 0.f), m0);
    m1 = fmaf(ww, fmaxf(tl1 - tiv, 0.f), m1);
    m2 = fmaf(ww, fmaxf(tl2 - tiv, 0.f), m2);
  }
  part[wvv][0][lane] = m0;
  part[wvv][1][lane] = m1;
  part[wvv][2][lane] = m2;
  __syncthreads();

  if (wvv == 0) {
    m0 = part[0][0][lane] + part[1][0][lane] + part[2][0][lane] + part[3][0][lane];
    m1 = part[0][1][lane] + part[1][1][lane] + part[2][1][lane] + part[3][1][lane];
    m2 = part[0][2][lane] + part[1][2][lane] + part[2][2][lane] + part[3][2][lane];
    unsigned long long b0 = __ballot(m0 >= 1.0f);
    unsigned long long b1 = __ballot(m1 >= 1.0f);
    unsigned long long b2 = __ballot(m2 >= 1.0f);
    b2 &= (1ull << 23) - 1;            // t <= 150
    b2 |= (1ull << 22);                // forced spike at t = 150
    int tres;
    if (b0)      tres = __ffsll((long long)b0) - 1;
    else if (b1) tres = 64 + __ffsll((long long)b1) - 1;
    else         tres = 128 + __ffsll((long long)b2) - 1;
    if (lane == 0) out[(size_t)b * F2_ + j] = (float)tres * DT_;
  }
}

}  // namespace

// ---------------------------------------------------------------------------
extern "C" void kernel_launch(void* const* d_in, const int* in_sizes, int n_in,
                              void* d_out, int out_size, void* d_ws, size_t ws_size,
                              hipStream_t stream) {
  const float* ti = (const float*)d_in[0];   // [64][1876]
  const float* W1 = (const float*)d_in[1];   // [1024][1876]
  const float* W2 = (const float*)d_in[2];   // [10][1024]
  float* out = (float*)d_out;                // [64][10]

  char* ws = (char*)d_ws;
  int*     W1iT = (int*)(ws + OFF_W1IT);
  uint2*   rec  = (uint2*)(ws + OFF_REC);
  uint8_t* idx1 = (uint8_t*)(ws + OFF_IDX1);

  hipLaunchKernelGGL(k_prep,  dim3(NBLK_T + NBLK_R), dim3(256), 0, stream,
                     W1, ti, W1iT, rec);
  hipLaunchKernelGGL(k_main1, dim3(256), dim3(256), 0, stream, rec, W1iT, idx1);
  hipLaunchKernelGGL(k_main2, dim3(640), dim3(256), 0, stream, idx1, W2, out);
}

// Round 16
// 70.304 us; speedup vs baseline: 7.0978x; 7.0978x over previous
//
#include <hip/hip_runtime.h>
#include <stdint.h>

namespace {

constexpr int   B_   = 64;
constexpr int   F0_  = 1876;
constexpr int   F0P_ = 1880;      // padded rec length (pads never processed)
constexpr int   NI4_ = 469;       // 1876 / 4 exact
constexpr int   F1_  = 1024;
constexpr int   F2_  = 10;
constexpr int   NT_  = 151;
constexpr float DT_  = 0.02f;
constexpr float SCL_  = 1073741824.0f;      // 2^30 fixed-point scale
constexpr float ISCL_ = 1.0f / 1073741824.0f;

constexpr int NBLK_T = 480;       // 30 i-tiles x 16 j-tiles
constexpr int NBLK_R = 470;       // 64*1880/256 exact

// workspace layout (bytes)
constexpr size_t OFF_W1I4 = 0;                     // 469*1024*16 = 7,684,096
constexpr size_t OFF_KOFF = 7684096;               // 64*1880*2   =   240,640
constexpr size_t OFF_TV   = 7924736;               // 64*1880*4   =   481,280
constexpr size_t OFF_IDX1 = 8406016;               // 64*1024 u8  =    65,536

// ---------------------------------------------------------------------------
// k_prep: (a) blocks < 480:  W1[j][i] f32 -> W1iT4[i4][j][4] int
//             (int4 per (i4,j): 4 consecutive i's weights, rn(w*2^30))
//         (b) blocks >= 480: koff16[b][i] = clamp(ceil(ti*50),0,50)*512 (u16,
//             bins row stride 64*8=512 B); tvarr[b][i] = ti.
// ---------------------------------------------------------------------------
__global__ __launch_bounds__(256) void k_prep(const float* __restrict__ W1,
                                              const float* __restrict__ ti,
                                              int4* __restrict__ W1iT4,
                                              uint16_t* __restrict__ koff16,
                                              float* __restrict__ tvarr) {
  const int t = threadIdx.x;
  if (blockIdx.x < NBLK_T) {
    __shared__ float tile[64][65];
    const int bx = blockIdx.x;
    const int i0 = (bx % 30) * 64;     // 0..1856
    const int j0 = (bx / 30) * 64;
    const int c = t & 63, r4 = t >> 6;
    for (int jj = r4; jj < 64; jj += 4) {
      int i = i0 + c;
      tile[c][jj] = (i < F0_) ? W1[(size_t)(j0 + jj) * F0_ + i] : 0.0f;
    }
    __syncthreads();
    for (int ii4 = r4; ii4 < 16; ii4 += 4) {
      int i4 = (i0 >> 2) + ii4;
      if (i4 < NI4_) {
        int4 v;
        v.x = __float2int_rn(tile[ii4 * 4 + 0][c] * SCL_);
        v.y = __float2int_rn(tile[ii4 * 4 + 1][c] * SCL_);
        v.z = __float2int_rn(tile[ii4 * 4 + 2][c] * SCL_);
        v.w = __float2int_rn(tile[ii4 * 4 + 3][c] * SCL_);
        W1iT4[(size_t)i4 * F1_ + j0 + c] = v;
      }
    }
  } else {
    int n = (blockIdx.x - NBLK_T) * 256 + t;     // < 120,320
    int b = n / F0P_, i = n - b * F0P_;
    if (i < F0_) {
      float v = ti[(size_t)b * F0_ + i];
      int k = (int)fminf(ceilf(v * 50.0f), 50.0f);   // ti >= 0 -> k >= 0
      koff16[n] = (uint16_t)(k << 9);                // k*512
      tvarr[n]  = v;
    } else {
      koff16[n] = 0;
      tvarr[n]  = 0.0f;                              // pads never processed
    }
  }
}

// ---------------------------------------------------------------------------
// Layer 1: 1024 blocks = b*16 + jg (XCD = jg%8 -> 960 KB W slice L2-fit),
// 512 threads = 8 waves, lane = j (wave-uniform bin k -> ds ops conflict-free
// BY CONSTRUCTION, r15-confirmed: 0 conflicts).  Waves split the 469 i4-range
// (r15 fix: 4 blocks/CU x 8 waves = 32 waves/CU of TLP instead of 4).
// Per i4: one dwordx4 W load (4 elems), one b64 + one b128 broadcast rec
// read from LDS, four packed ds_add_u64 into shared bins[51][64].
// pk = (a<<32)|(c mod 2^32); int adds commute -> bit-deterministic; per-bin
// sums < 2^31 so borrow-corrected unpack is exact (r13/r14, absmax 0.0).
// Phase 2: wave 0 per-thread fused prefix+crossing scan.
// LDS 37.4 KB -> 4 blocks/CU.
// ---------------------------------------------------------------------------
__global__ __launch_bounds__(512, 8) void k_main1(const uint16_t* __restrict__ koff16,
                                                  const float* __restrict__ tvarr,
                                                  const int4* __restrict__ W1iT4,
                                                  uint8_t* __restrict__ idx1) {
  __shared__ unsigned long long bins[51][64];    // 26,112 B
  __shared__ uint16_t lkoff[F0P_];               //  3,760 B
  __shared__ float    ltv[F0P_];                 //  7,520 B
  const int blk  = blockIdx.x;        // 1024
  const int b    = blk >> 4;
  const int jg   = blk & 15;
  const int tid  = threadIdx.x;
  const int lane = tid & 63;
  const int wv   = __builtin_amdgcn_readfirstlane(tid >> 6);  // 0..7

  {
    int4* p = (int4*)(&bins[0][0]);
    for (int s = tid; s < (int)(sizeof(bins) / 16); s += 512)
      p[s] = make_int4(0, 0, 0, 0);
    const uint32_t* ks = (const uint32_t*)(koff16 + (size_t)b * F0P_);
    uint32_t* kd = (uint32_t*)lkoff;
    for (int s = tid; s < F0P_ / 2; s += 512) kd[s] = ks[s];
    const float* ts = tvarr + (size_t)b * F0P_;
    for (int s = tid; s < F0P_; s += 512) ltv[s] = ts[s];
  }
  __syncthreads();

  // wave i4-split: 469 = 8*58 + 5
  const int cnt = 58 + (wv < 5 ? 1 : 0);
  const int g0  = wv * 58 + (wv < 5 ? wv : 5);

  const int4* __restrict__ wp = W1iT4 + (jg << 6) + lane;   // + i4*1024
  char* const binlane = (char*)(&bins[0][0]) + (lane << 3);

#define ELEM(a_, tv_, ko_) {                                                  \
    int   c_ = __float2int_rn((float)(a_) * (tv_));                           \
    unsigned long long pk =                                                   \
        ((unsigned long long)(unsigned)(a_) << 32) | (unsigned)(c_);          \
    atomicAdd((unsigned long long*)(binlane + (ko_)), pk); }

#pragma unroll 2
  for (int m = 0; m < cnt; ++m) {
    const int i4 = g0 + m;
    int4   wa  = wp[(size_t)i4 << 10];                 // coalesced 1 KB/wave
    uint2  kk  = *(const uint2*)(lkoff + i4 * 4);      // broadcast b64
    float4 tv4 = *(const float4*)(ltv + i4 * 4);       // broadcast b128
    ELEM(wa.x, tv4.x, kk.x & 0xFFFFu);
    ELEM(wa.y, tv4.y, kk.x >> 16);
    ELEM(wa.z, tv4.z, kk.y & 0xFFFFu);
    ELEM(wa.w, tv4.w, kk.y >> 16);
  }
#undef ELEM
  __syncthreads();

  // phase 2: wave 0, lane = j. Fused per-bin unpack + prefix + crossing.
  if (tid < 64) {
    float sa = 0.f, sc = 0.f;
    int cnd = NT_;
#pragma unroll 1
    for (int tt = 0; tt < NT_; ++tt) {
      if (tt < 51) {
        unsigned long long s = bins[tt][tid];
        int cl = (int)(unsigned)(s & 0xFFFFFFFFull);
        int ah = (int)(unsigned)(s >> 32);
        if (cl < 0) ah += 1;                   // borrow correction (exact)
        sa += (float)ah * ISCL_;
        sc += (float)cl * ISCL_;
      }
      float mv = (float)tt * DT_ * sa - sc;
      if (cnd == NT_ && mv >= 1.0f) cnd = tt;
    }
    cnd = min(cnd, NT_ - 1);                   // forced spike at last step
    idx1[((size_t)b << 10) + (jg << 6) + tid] = (uint8_t)cnd;
  }
}

// ---------------------------------------------------------------------------
// Layer-2: brute force. Block = (b,j), 4 waves split the i-range; lane = t.
// (unchanged, proven)
// ---------------------------------------------------------------------------
__global__ __launch_bounds__(256) void k_main2(const uint8_t* __restrict__ idx1,
                                               const float* __restrict__ W2,
                                               float* __restrict__ out) {
  __shared__ float wrow[F1_];
  __shared__ float tirow[F1_];
  __shared__ float part[4][3][64];
  const int blk = blockIdx.x;          // 640
  const int b   = blk / 10;
  const int j   = blk - b * 10;
  const int tid = threadIdx.x;
  const int lane = tid & 63, wvv = tid >> 6;

  const float*   w = W2  + (size_t)j * F1_;
  const uint8_t* h = idx1 + (size_t)b * F1_;
  for (int s = tid; s < F1_; s += 256) {
    wrow[s]  = w[s];
    tirow[s] = (float)h[s] * DT_;
  }
  __syncthreads();

  const float tl0 = (float)lane * DT_;
  const float tl1 = (float)(lane + 64) * DT_;
  const float tl2 = (float)(lane + 128) * DT_;
  float m0 = 0.f, m1 = 0.f, m2 = 0.f;
  const int i0 = wvv * 256;
#pragma unroll 4
  for (int i = i0; i < i0 + 256; ++i) {
    float tiv = tirow[i], ww = wrow[i];
    m0 = fmaf(ww, fmaxf(tl0 - tiv, 0.f), m0);
    m1 = fmaf(ww, fmaxf(tl1 - tiv, 0.f), m1);
    m2 = fmaf(ww, fmaxf(tl2 - tiv, 0.f), m2);
  }
  part[wvv][0][lane] = m0;
  part[wvv][1][lane] = m1;
  part[wvv][2][lane] = m2;
  __syncthreads();

  if (wvv == 0) {
    m0 = part[0][0][lane] + part[1][0][lane] + part[2][0][lane] + part[3][0][lane];
    m1 = part[0][1][lane] + part[1][1][lane] + part[2][1][lane] + part[3][1][lane];
    m2 = part[0][2][lane] + part[1][2][lane] + part[2][2][lane] + part[3][2][lane];
    unsigned long long b0 = __ballot(m0 >= 1.0f);
    unsigned long long b1 = __ballot(m1 >= 1.0f);
    unsigned long long b2 = __ballot(m2 >= 1.0f);
    b2 &= (1ull << 23) - 1;            // t <= 150
    b2 |= (1ull << 22);                // forced spike at t = 150
    int tres;
    if (b0)      tres = __ffsll((long long)b0) - 1;
    else if (b1) tres = 64 + __ffsll((long long)b1) - 1;
    else         tres = 128 + __ffsll((long long)b2) - 1;
    if (lane == 0) out[(size_t)b * F2_ + j] = (float)tres * DT_;
  }
}

}  // namespace

// ---------------------------------------------------------------------------
extern "C" void kernel_launch(void* const* d_in, const int* in_sizes, int n_in,
                              void* d_out, int out_size, void* d_ws, size_t ws_size,
                              hipStream_t stream) {
  const float* ti = (const float*)d_in[0];   // [64][1876]
  const float* W1 = (const float*)d_in[1];   // [1024][1876]
  const float* W2 = (const float*)d_in[2];   // [10][1024]
  float* out = (float*)d_out;                // [64][10]

  char* ws = (char*)d_ws;
  int4*     W1iT4 = (int4*)(ws + OFF_W1I4);
  uint16_t* koff  = (uint16_t*)(ws + OFF_KOFF);
  float*    tvs   = (float*)(ws + OFF_TV);
  uint8_t*  idx1  = (uint8_t*)(ws + OFF_IDX1);

  hipLaunchKernelGGL(k_prep,  dim3(NBLK_T + NBLK_R), dim3(256), 0, stream,
                     W1, ti, W1iT4, koff, tvs);
  hipLaunchKernelGGL(k_main1, dim3(1024), dim3(512), 0, stream,
                     koff, tvs, W1iT4, idx1);
  hipLaunchKernelGGL(k_main2, dim3(640),  dim3(256), 0, stream, idx1, W2, out);
}